// Round 8
// baseline (267.891 us; speedup 1.0000x reference)
//
#include <hip/hip_runtime.h>

#define BATCH 64
#define M_GT  100
#define M1    101
#define NANCH 8732
#define BLOCK 256
#define TROW  8

// Role B: fused argmax + epilogue (writes out_labeled only)
#define B_NX    35                       // ceil(8732/256)
#define NBLK_B  (B_NX * BATCH)           // 2240

// Role A: (b, 4 m-rows) per block, sweeping all n -> contiguous row writes
#define A_MCH   4
#define A_NCH   26                       // ceil(101/4): 25 full chunks + 1 single
#define A_NPT   4
#define A_STEP  (BLOCK * A_NPT)          // 1024 anchors per sweep iteration
#define NBLK_A  (BATCH * A_NCH)          // 1664
#define NBLK    (NBLK_A + NBLK_B)        // 3904

// Prep: padded GT table in d_ws. Row: {x1,y1,x2,y2,area_or_inf,cls,0,0}.
// Pad row (m=0) and invalid rows (cls==0) get area=+inf ->
// iou = inter * rcp(inf) = +0 exactly (masking), never NaN.
__global__ __launch_bounds__(128) void prep_table(
    const float* __restrict__ labels,   // [B, M, 5]
    float* __restrict__ tab)            // [B, M1, TROW]
{
    const int b = blockIdx.x;
    const int m = threadIdx.x;
    if (m >= M1) return;
    float x1 = 0.f, y1 = 0.f, x2 = 0.f, y2 = 0.f, cls = 0.f;
    float ar = __builtin_inff();
    if (m >= 1) {
        const float* row = labels + ((size_t)b * M_GT + (m - 1)) * 5;
        x1 = row[0]; y1 = row[1]; x2 = row[2]; y2 = row[3]; cls = row[4];
        if (cls != 0.0f) ar = (x2 - x1) * (y2 - y1);
    }
    float* t = tab + ((size_t)b * M1 + m) * TROW;
    t[0] = x1; t[1] = y1; t[2] = x2; t[3] = y2;
    t[4] = ar; t[5] = cls; t[6] = 0.f; t[7] = 0.f;
}

__device__ __forceinline__ float iou_rcp(float gx1, float gy1, float gx2, float gy2,
                                         float ga, float ax1, float ay1, float ax2,
                                         float ay2, float aa) {
    const float ix1 = fmaxf(gx1, ax1), iy1 = fmaxf(gy1, ay1);
    const float ix2 = fminf(gx2, ax2), iy2 = fminf(gy2, ay2);
    const float iw = fmaxf(ix2 - ix1, 0.0f), ih = fmaxf(iy2 - iy1, 0.0f);
    const float inter = iw * ih;
    return inter * __builtin_amdgcn_rcpf(ga + aa - inter);  // validated R3/R7
}

__global__ __launch_bounds__(BLOCK, 6) void encode_main(
    const float* __restrict__ tab,      // [B, M1, TROW] (uniform -> s_load)
    const float* __restrict__ dboxes,   // [N, 4]
    float* __restrict__ out_labeled,    // [B, N, 5]
    float* __restrict__ out_ious)       // [B, M1, N]
{
    const int tid = threadIdx.x;
    const int gid = blockIdx.x;

    if (gid < NBLK_B) {
        // ---------------- Role B: argmax + epilogue ----------------
        const int b = gid / B_NX;
        const int n = (gid % B_NX) * BLOCK + tid;
        if (n >= NANCH) return;

        const float4 d = *reinterpret_cast<const float4*>(dboxes + (size_t)n * 4);
        const float ax1 = d.x, ay1 = d.y, ax2 = d.z, ay2 = d.w;
        const float aa  = (ax2 - ax1) * (ay2 - ay1);

        const float* r = tab + (size_t)b * M1 * TROW;
        float best = -1.0f; int besti = 0;
        #pragma unroll 4
        for (int m = 0; m < M1; ++m, r += TROW) {
            const float iou = iou_rcp(r[0], r[1], r[2], r[3], r[4],
                                      ax1, ay1, ax2, ay2, aa);
            if (iou > best) { best = iou; besti = m; }  // strict > = first occurrence
        }

        const int idx = (best > 0.5f) ? besti : 0;
        float ox = 0.f, oy = 0.f, ow = 0.f, oh = 0.f, pcls = 0.f;
        if (idx != 0) {   // iou>0.5 winner is always a valid (cls!=0) row
            const float* t = tab + ((size_t)b * M1 + idx) * TROW;
            const float x1 = t[0], y1 = t[1], x2 = t[2], y2 = t[3];
            const float aw = ax2 - ax1, ah = ay2 - ay1;
            ox = (0.5f * (x1 + x2) - 0.5f * (ax1 + ax2)) / aw;
            oy = (0.5f * (y1 + y2) - 0.5f * (ay1 + ay2)) / ah;
            ow = __logf((x2 - x1) / aw);
            oh = __logf((y2 - y1) / ah);
            pcls = t[5];
        }
        float* lrow = out_labeled + ((size_t)b * NANCH + n) * 5;
        lrow[0] = ox; lrow[1] = oy; lrow[2] = ow; lrow[3] = oh; lrow[4] = pcls;
    } else {
        // ------- Role A: contiguous row-sweep iou writes (fill-shaped) -------
        const int g  = gid - NBLK_B;
        const int b  = g / A_NCH;
        const int mc = g % A_NCH;
        const int m0 = mc * A_MCH;

        const float* r = tab + ((size_t)b * M1 + m0) * TROW;
        float* wbase = out_ious + ((size_t)b * M1 + m0) * NANCH;

        if (m0 + A_MCH <= M1) {
            float gx1[A_MCH], gy1[A_MCH], gx2[A_MCH], gy2[A_MCH], ga[A_MCH];
            #pragma unroll
            for (int j = 0; j < A_MCH; ++j) {
                gx1[j] = r[j*TROW+0]; gy1[j] = r[j*TROW+1];
                gx2[j] = r[j*TROW+2]; gy2[j] = r[j*TROW+3];
                ga[j]  = r[j*TROW+4];
            }
            for (int n0 = tid * A_NPT; n0 < NANCH; n0 += A_STEP) {
                float ax1[A_NPT], ay1[A_NPT], ax2[A_NPT], ay2[A_NPT], aa[A_NPT];
                #pragma unroll
                for (int i = 0; i < A_NPT; ++i) {
                    const float4 d = *reinterpret_cast<const float4*>(dboxes + (size_t)(n0 + i) * 4);
                    ax1[i] = d.x; ay1[i] = d.y; ax2[i] = d.z; ay2[i] = d.w;
                    aa[i]  = (d.z - d.x) * (d.w - d.y);
                }
                #pragma unroll
                for (int j = 0; j < A_MCH; ++j) {
                    float iou[A_NPT];
                    #pragma unroll
                    for (int i = 0; i < A_NPT; ++i)
                        iou[i] = iou_rcp(gx1[j], gy1[j], gx2[j], gy2[j], ga[j],
                                         ax1[i], ay1[i], ax2[i], ay2[i], aa[i]);
                    float4 w; w.x = iou[0]; w.y = iou[1]; w.z = iou[2]; w.w = iou[3];
                    *reinterpret_cast<float4*>(wbase + (size_t)j * NANCH + n0) = w;
                }
            }
        } else {
            // tail chunk: exactly one m-row (m0 == 100)
            const float gx1 = r[0], gy1 = r[1], gx2 = r[2], gy2 = r[3], ga = r[4];
            for (int n0 = tid * A_NPT; n0 < NANCH; n0 += A_STEP) {
                float iou[A_NPT];
                #pragma unroll
                for (int i = 0; i < A_NPT; ++i) {
                    const float4 d = *reinterpret_cast<const float4*>(dboxes + (size_t)(n0 + i) * 4);
                    iou[i] = iou_rcp(gx1, gy1, gx2, gy2, ga, d.x, d.y, d.z, d.w,
                                     (d.z - d.x) * (d.w - d.y));
                }
                float4 w; w.x = iou[0]; w.y = iou[1]; w.z = iou[2]; w.w = iou[3];
                *reinterpret_cast<float4*>(wbase + n0) = w;
            }
        }
    }
}

extern "C" void kernel_launch(void* const* d_in, const int* in_sizes, int n_in,
                              void* d_out, int out_size, void* d_ws, size_t ws_size,
                              hipStream_t stream) {
    const float* labels = (const float*)d_in[0];
    const float* dboxes = (const float*)d_in[1];
    float* out_labeled = (float*)d_out;
    float* out_ious    = out_labeled + (size_t)BATCH * NANCH * 5;
    float* tab         = (float*)d_ws;   // 207 KB << ws_size

    prep_table<<<dim3(BATCH), dim3(128), 0, stream>>>(labels, tab);
    encode_main<<<dim3(NBLK), dim3(BLOCK), 0, stream>>>(tab, dboxes, out_labeled, out_ious);
}

// Round 9
// 247.441 us; speedup vs baseline: 1.0826x; 1.0826x over previous
//
#include <hip/hip_runtime.h>

#define BATCH 64
#define M_GT  100
#define M1    101
#define NANCH 8732
#define BLOCK 256
#define NPT   4                    // anchors per thread -> dwordx4 stores
#define NTILE (BLOCK * NPT)        // 1024
#define NX    9                    // ceil(8732/1024)
#define NBLK  (NX * BATCH)         // 576 blocks

// Single fused dispatch. Each block builds the 101-row GT table in LDS
// (redundant across blocks but ~1 µs total, L2-served; removes the prep
// kernel graph node). Masking: pad row (m=0) and invalid rows (cls==0) get
// area=+inf -> iou = inter * rcp(inf) = +0 exactly, never NaN.
__global__ __launch_bounds__(BLOCK) void encode_fused(
    const float* __restrict__ labels,   // [B, M, 5]
    const float* __restrict__ dboxes,   // [N, 4]
    float* __restrict__ out_labeled,    // [B, N, 5]
    float* __restrict__ out_ious)       // [B, M1, N]
{
    __shared__ float4 s_box[M1];        // {x1,y1,x2,y2}
    __shared__ float  s_ar[M1], s_cls[M1];

    const int tid = threadIdx.x;
    const int b   = blockIdx.x / NX;
    const int nb  = blockIdx.x % NX;

    if (tid < M1) {
        float x1 = 0.f, y1 = 0.f, x2 = 0.f, y2 = 0.f, cls = 0.f;
        float ar = __builtin_inff();
        if (tid >= 1) {
            const float* row = labels + ((size_t)b * M_GT + (tid - 1)) * 5;
            x1 = row[0]; y1 = row[1]; x2 = row[2]; y2 = row[3]; cls = row[4];
            if (cls != 0.0f) ar = (x2 - x1) * (y2 - y1);
        }
        s_box[tid] = make_float4(x1, y1, x2, y2);
        s_ar[tid] = ar; s_cls[tid] = cls;
    }
    __syncthreads();

    const int n0 = nb * NTILE + tid * NPT;
    if (n0 >= NANCH) return;           // NANCH % 4 == 0 -> whole quad in/out

    float ax1[NPT], ay1[NPT], ax2[NPT], ay2[NPT], aa[NPT];
    #pragma unroll
    for (int i = 0; i < NPT; ++i) {
        const float4 d = *reinterpret_cast<const float4*>(dboxes + (size_t)(n0 + i) * 4);
        ax1[i] = d.x; ay1[i] = d.y; ax2[i] = d.z; ay2[i] = d.w;
        aa[i]  = (d.z - d.x) * (d.w - d.y);
    }

    float* irow = out_ious + (size_t)b * M1 * NANCH + n0;

    // best=-1: pad rows give iou=+0; strict > = numpy first-occurrence argmax.
    float best[NPT]; int besti[NPT];
    #pragma unroll
    for (int i = 0; i < NPT; ++i) { best[i] = -1.0f; besti[i] = 0; }

    #pragma unroll 4
    for (int m = 0; m < M1; ++m) {
        const float4 g = s_box[m];      // ds_read_b128 broadcast
        const float ga = s_ar[m];       // ds_read_b32 broadcast
        float iou[NPT];
        #pragma unroll
        for (int i = 0; i < NPT; ++i) {
            const float ix1 = fmaxf(g.x, ax1[i]), iy1 = fmaxf(g.y, ay1[i]);
            const float ix2 = fminf(g.z, ax2[i]), iy2 = fminf(g.w, ay2[i]);
            const float iw = fmaxf(ix2 - ix1, 0.0f), ih = fmaxf(iy2 - iy1, 0.0f);
            const float inter = iw * ih;
            iou[i] = inter * __builtin_amdgcn_rcpf(ga + aa[i] - inter);  // validated R3/R7
            if (iou[i] > best[i]) { best[i] = iou[i]; besti[i] = m; }
        }
        float4 w; w.x = iou[0]; w.y = iou[1]; w.z = iou[2]; w.w = iou[3];
        *reinterpret_cast<float4*>(irow) = w;   // 1KB per wave-instr
        irow += NANCH;
    }

    // Epilogue
    float lw[NPT * 5];
    #pragma unroll
    for (int i = 0; i < NPT; ++i) {
        const int idx = (best[i] > 0.5f) ? besti[i] : 0;
        float ox = 0.f, oy = 0.f, ow = 0.f, oh = 0.f, pcls = 0.f;
        if (idx != 0) {   // iou>0.5 winner is always a valid (cls!=0) row
            const float4 t = s_box[idx];
            const float aw = ax2[i] - ax1[i], ah = ay2[i] - ay1[i];
            ox = (0.5f * (t.x + t.z) - 0.5f * (ax1[i] + ax2[i])) / aw;
            oy = (0.5f * (t.y + t.w) - 0.5f * (ay1[i] + ay2[i])) / ah;
            ow = __logf((t.z - t.x) / aw);
            oh = __logf((t.w - t.y) / ah);
            pcls = s_cls[idx];
        }
        lw[i * 5 + 0] = ox; lw[i * 5 + 1] = oy; lw[i * 5 + 2] = ow;
        lw[i * 5 + 3] = oh; lw[i * 5 + 4] = pcls;
    }
    // 20 contiguous floats = 80B, 16B-aligned (n0 % 4 == 0)
    float* lrow = out_labeled + ((size_t)b * NANCH + n0) * 5;
    #pragma unroll
    for (int k = 0; k < 5; ++k) {
        float4 v; v.x = lw[k*4]; v.y = lw[k*4+1]; v.z = lw[k*4+2]; v.w = lw[k*4+3];
        *reinterpret_cast<float4*>(lrow + k * 4) = v;
    }
}

extern "C" void kernel_launch(void* const* d_in, const int* in_sizes, int n_in,
                              void* d_out, int out_size, void* d_ws, size_t ws_size,
                              hipStream_t stream) {
    const float* labels = (const float*)d_in[0];
    const float* dboxes = (const float*)d_in[1];
    float* out_labeled = (float*)d_out;
    float* out_ious    = out_labeled + (size_t)BATCH * NANCH * 5;

    encode_fused<<<dim3(NBLK), dim3(BLOCK), 0, stream>>>(labels, dboxes, out_labeled, out_ious);
}